// Round 10
// baseline (171.073 us; speedup 1.0000x reference)
//
#include <hip/hip_runtime.h>
#include <hip/hip_bf16.h>

#define CC 16
#define BB 16384
#define DD 256
#define NT 512
#define SLAB ((size_t)BB * DD)

typedef float f32x4 __attribute__((ext_vector_type(4)));
typedef short bf16x8 __attribute__((ext_vector_type(8)));
typedef short bf16x4 __attribute__((ext_vector_type(4)));

static __device__ __forceinline__ short bfc(float f) {
    return (short)__builtin_bit_cast(unsigned short, __float2bfloat16(f));
}
static __device__ __forceinline__ bf16x8 pack8(f32x4 a, f32x4 b) {
    bf16x8 v;
    v[0] = bfc(a[0]); v[1] = bfc(a[1]); v[2] = bfc(a[2]); v[3] = bfc(a[3]);
    v[4] = bfc(b[0]); v[5] = bfc(b[1]); v[6] = bfc(b[2]); v[7] = bfc(b[3]);
    return v;
}
static __device__ __forceinline__ float sigm(float x) {
    return __builtin_amdgcn_rcpf(1.0f + __expf(-x));
}
static __device__ __forceinline__ float tanh_(float x) {
    return 2.0f * __builtin_amdgcn_rcpf(1.0f + __expf(-2.0f * x)) - 1.0f;
}

typedef __attribute__((address_space(3))) void lds_void;
typedef const __attribute__((address_space(1))) void gl_void;
static __device__ __forceinline__ void stage16(const void* g, void* l) {
    __builtin_amdgcn_global_load_lds((gl_void*)g, (lds_void*)l, 16, 0, 0);
}

// ---- prep: pack Wf (rows 0..255) + Wiou (rows 256..1023) f32 -> bf16
__global__ void prep(const float* __restrict__ Wf, const float* __restrict__ Wiou,
                     short* __restrict__ ws) {
    const int row = blockIdx.x;
    const int t   = threadIdx.x;
    const float* src = (row < 256) ? (Wf + (size_t)row * DD)
                                   : (Wiou + (size_t)(row - 256) * DD);
    f32x4 v = *(const f32x4*)(src + t * 4);
    bf16x4 o; o[0] = bfc(v[0]); o[1] = bfc(v[1]); o[2] = bfc(v[2]); o[3] = bfc(v[3]);
    *(bf16x4*)(ws + (size_t)row * DD + t * 4) = o;
}

// ---- main: TreeLSTM, ALL memory deadlines >= 2 phases.
// 512 thr = 8 waves; block = 16 rows x 256 cols; wave owns 32 output cols.
// h: global_load_lds f32 triple buffer, staged 2 children ahead (R9-proven,
// 0 conflicts). cm: register prefetch distance 2 via THREE rotating banks
// with static indices (period-3 macro unroll) — no sub-phase deadline left.
// Every phase issues exactly 10 VMEM/wave; constant vmcnt(18) + raw s_barrier.
__global__ __launch_bounds__(NT, 2) void treelstm(
    const float* __restrict__ cmem,   // [C][B][D]
    const float* __restrict__ chid,   // [C][B][D]
    const short* __restrict__ wpk,    // bf16: Wf rows 0..255, Wiou 256..1023
    const float* __restrict__ bfv,    // [D]
    const float* __restrict__ biou,   // [3D]
    float* __restrict__ out)          // [2][B][D]
{
    __shared__ __align__(1024) unsigned char hb[3][16 * 1024];   // 48 KiB f32 tiles

    const int tid  = threadIdx.x;
    const int lane = tid & 63;
    const int wid  = tid >> 6;     // 0..7
    const int l15  = lane & 15;
    const int l4   = lane >> 4;    // 0..3
    const int b0   = blockIdx.x * 16;
    const int wc0  = wid * 32;

    // ---- weight fragments first (program-order pinned before staging)
    bf16x8 wfr[2][8];
    float bfr[2];
#pragma unroll
    for (int n = 0; n < 2; ++n) {
        const short* wr = wpk + (size_t)(wc0 + n * 16 + l15) * DD + l4 * 8;
#pragma unroll
        for (int k = 0; k < 8; ++k) wfr[n][k] = *(const bf16x8*)(wr + k * 32);
        bfr[n] = bfv[wc0 + n * 16 + l15];
    }
    __builtin_amdgcn_sched_barrier(0);

    // ---- staging geometry: wave stages rows r0=2wid, r1=2wid+1 (1 row/instr).
    // phys granule lane -> logical (lane&32)|((lane&31)^row)  (self-inverse)
    const int r0 = 2 * wid, r1 = r0 + 1;
    const int g0 = (lane & 32) | ((lane & 31) ^ r0);
    const int g1 = (lane & 32) | ((lane & 31) ^ r1);
    const float* hsrc0 = chid + (size_t)(b0 + r0) * DD + g0 * 4;
    const float* hsrc1 = chid + (size_t)(b0 + r1) * DD + g1 * 4;

    unsigned char* pc = &hb[0][0];   // holds h(c)
    unsigned char* pn = &hb[1][0];   // holds h(c+1)
    unsigned char* pf = &hb[2][0];   // staging target h(c+2)

    // ---- prologue: stage h(0)->buf0, h(1)->buf1; cm(0)->A, cm(1)->B
    stage16(hsrc0, pc + r0 * 1024);
    stage16(hsrc1, pc + r1 * 1024);
    stage16(hsrc0 + SLAB, pn + r0 * 1024);
    stage16(hsrc1 + SLAB, pn + r1 * 1024);

    const float* cmp = cmem + (size_t)(b0 + l4 * 4) * DD + wc0 + l15;
    float cmA[8], cmB[8], cmD[8];
#pragma unroll
    for (int n = 0; n < 2; ++n)
#pragma unroll
        for (int j = 0; j < 4; ++j) cmA[n * 4 + j] = cmp[j * DD + n * 16];
    {
        const float* cn = cmp + SLAB;
#pragma unroll
        for (int n = 0; n < 2; ++n)
#pragma unroll
            for (int j = 0; j < 4; ++j) cmB[n * 4 + j] = cn[j * DD + n * 16];
    }

    __builtin_amdgcn_sched_barrier(0);
    asm volatile("s_waitcnt vmcnt(18)" ::: "memory");   // h(0) staged
    __builtin_amdgcn_s_barrier();
    __builtin_amdgcn_sched_barrier(0);

    float hs[8], nmv[8];
#pragma unroll
    for (int i = 0; i < 8; ++i) { hs[i] = 0.f; nmv[i] = 0.f; }

// Phase c: consume h(c) (from pc) and cm bank CUR=cm(c); issue stage h(c+2)
// and cm(c+2)->FUT. 10 VMEM/phase (clamped tail); vmcnt(18)+barrier at bottom
// guarantees h(c+1) staged; cm consumption waits are compiler-counted and
// ~2 phases after issue.
#define CHILD(c, CUR, FUT)                                                    \
    {                                                                         \
        const int hc = ((c) + 2 < CC) ? (c) + 2 : CC - 1;                     \
        stage16(hsrc0 + (size_t)hc * SLAB, pf + r0 * 1024);                   \
        stage16(hsrc1 + (size_t)hc * SLAB, pf + r1 * 1024);                   \
        {                                                                     \
            const float* cn = cmp + (size_t)hc * SLAB;                        \
            _Pragma("unroll") for (int n = 0; n < 2; ++n)                     \
            _Pragma("unroll") for (int j = 0; j < 4; ++j)                     \
                FUT[n * 4 + j] = cn[j * DD + n * 16];                         \
        }                                                                     \
        __builtin_amdgcn_sched_barrier(0);                                    \
        f32x4 acc0 = {bfr[0], bfr[0], bfr[0], bfr[0]};                        \
        f32x4 acc1 = {bfr[1], bfr[1], bfr[1], bfr[1]};                        \
        const unsigned char* bc = pc + l15 * 1024;                            \
        _Pragma("unroll") for (int kk = 0; kk < 8; ++kk) {                    \
            const int half = (kk >> 2) * 512;                                 \
            const int gl = (kk & 3) * 8 + l4 * 2;                             \
            f32x4 x0 = *(const f32x4*)(bc + half + ((gl ^ l15) << 4));        \
            f32x4 x1 = *(const f32x4*)(bc + half + (((gl + 1) ^ l15) << 4));  \
            if (kk == wid) {                                                  \
                _Pragma("unroll") for (int i = 0; i < 4; ++i) {               \
                    hs[i] += x0[i]; hs[4 + i] += x1[i];                       \
                }                                                             \
            }                                                                 \
            bf16x8 a = pack8(x0, x1);                                         \
            acc0 = __builtin_amdgcn_mfma_f32_16x16x32_bf16(a, wfr[0][kk], acc0, 0, 0, 0); \
            acc1 = __builtin_amdgcn_mfma_f32_16x16x32_bf16(a, wfr[1][kk], acc1, 0, 0, 0); \
        }                                                                     \
        _Pragma("unroll") for (int j = 0; j < 4; ++j) {                       \
            nmv[j]     += sigm(acc0[j]) * CUR[j];                             \
            nmv[4 + j] += sigm(acc1[j]) * CUR[4 + j];                         \
        }                                                                     \
        { unsigned char* t = pc; pc = pn; pn = pf; pf = t; }                  \
        asm volatile("s_waitcnt vmcnt(18)" ::: "memory");                     \
        __builtin_amdgcn_s_barrier();                                         \
        __builtin_amdgcn_sched_barrier(0);                                    \
    }

#pragma unroll 1
    for (int cc = 0; cc < 15; cc += 3) {      // children 0..14 in bank-rotation triples
        CHILD(cc,     cmA, cmD);
        CHILD(cc + 1, cmB, cmA);
        CHILD(cc + 2, cmD, cmB);
    }
    CHILD(15, cmA, cmD);                      // child 15 (cm(15) landed in A at c=13)
#undef CHILD

    // ---- epilogue: hidden_sum -> hb[0] (same swizzled layout)
    {
        unsigned char* wbuf = &hb[0][0];
        const int glo = (wid & 3) * 8 + l4 * 2;
        const int half = (wid >> 2) * 512;
        f32x4 s0 = {hs[0], hs[1], hs[2], hs[3]};
        f32x4 s1 = {hs[4], hs[5], hs[6], hs[7]};
        *(f32x4*)(wbuf + l15 * 1024 + half + ((glo ^ l15) << 4)) = s0;
        *(f32x4*)(wbuf + l15 * 1024 + half + (((glo + 1) ^ l15) << 4)) = s1;
    }
    asm volatile("s_waitcnt lgkmcnt(0)" ::: "memory");
    __builtin_amdgcn_s_barrier();
    __builtin_amdgcn_sched_barrier(0);

    bf16x8 afr[8];
    {
        const unsigned char* bc = &hb[0][0] + l15 * 1024;
#pragma unroll
        for (int kk = 0; kk < 8; ++kk) {
            const int half = (kk >> 2) * 512;
            const int gl = (kk & 3) * 8 + l4 * 2;
            f32x4 x0 = *(const f32x4*)(bc + half + ((gl ^ l15) << 4));
            f32x4 x1 = *(const f32x4*)(bc + half + (((gl + 1) ^ l15) << 4));
            afr[kk] = pack8(x0, x1);
        }
    }

    // ---- iou GEMM from packed Wiou
    float gq[3][8];
#pragma unroll
    for (int q = 0; q < 3; ++q) {
#pragma unroll
        for (int n = 0; n < 2; ++n) {
            const short* wr = wpk + (size_t)(256 + q * 256 + wc0 + n * 16 + l15) * DD + l4 * 8;
            f32x4 acc = {0.f, 0.f, 0.f, 0.f};
#pragma unroll
            for (int kk = 0; kk < 8; ++kk)
                acc = __builtin_amdgcn_mfma_f32_16x16x32_bf16(afr[kk], *(const bf16x8*)(wr + kk * 32), acc, 0, 0, 0);
            float bq = biou[q * 256 + wc0 + n * 16 + l15];
#pragma unroll
            for (int j = 0; j < 4; ++j) gq[q][n * 4 + j] = acc[j] + bq;
        }
    }

    // ---- gates + stores
    float* o0p = out + (size_t)(b0 + l4 * 4) * DD + wc0 + l15;
    float* o1p = o0p + SLAB;
#pragma unroll
    for (int n = 0; n < 2; ++n)
#pragma unroll
        for (int j = 0; j < 4; ++j) {
            float ig = sigm(gq[0][n * 4 + j]);
            float og = sigm(gq[1][n * 4 + j]);
            float ug = tanh_(gq[2][n * 4 + j]);
            float mm = nmv[n * 4 + j] + ig * ug;
            float hh = og * tanh_(mm);
            o0p[j * DD + n * 16] = mm;
            o1p[j * DD + n * 16] = hh;
        }
}

extern "C" void kernel_launch(void* const* d_in, const int* in_sizes, int n_in,
                              void* d_out, int out_size, void* d_ws, size_t ws_size,
                              hipStream_t stream) {
    const float* cmem = (const float*)d_in[0];
    const float* chid = (const float*)d_in[1];
    const float* Wf   = (const float*)d_in[2];
    const float* bf   = (const float*)d_in[3];
    const float* Wiou = (const float*)d_in[4];
    const float* biou = (const float*)d_in[5];
    float* out = (float*)d_out;
    short* wpk = (short*)d_ws;    // 1024 x 256 bf16 = 512 KiB

    prep<<<1024, 64, 0, stream>>>(Wf, Wiou, wpk);
    treelstm<<<BB / 16, NT, 0, stream>>>(cmem, chid, wpk, bf, biou, out);
}

// Round 11
// 161.307 us; speedup vs baseline: 1.0605x; 1.0605x over previous
//
#include <hip/hip_runtime.h>
#include <hip/hip_bf16.h>

#define CC 16
#define BB 16384
#define DD 256
#define BT 16
#define NT 512
#define SLAB ((size_t)BB * DD)

typedef float f32x4 __attribute__((ext_vector_type(4)));
typedef short bf16x8 __attribute__((ext_vector_type(8)));
typedef short bf16x4 __attribute__((ext_vector_type(4)));

static __device__ __forceinline__ short bfc(float f) {
    return (short)__builtin_bit_cast(unsigned short, __float2bfloat16(f));
}
static __device__ __forceinline__ bf16x8 pack8(f32x4 a, f32x4 b) {
    bf16x8 v;
    v[0] = bfc(a[0]); v[1] = bfc(a[1]); v[2] = bfc(a[2]); v[3] = bfc(a[3]);
    v[4] = bfc(b[0]); v[5] = bfc(b[1]); v[6] = bfc(b[2]); v[7] = bfc(b[3]);
    return v;
}
static __device__ __forceinline__ float sigm(float x) {
    return __builtin_amdgcn_rcpf(1.0f + __expf(-x));
}
static __device__ __forceinline__ float tanh_(float x) {
    return 2.0f * __builtin_amdgcn_rcpf(1.0f + __expf(-2.0f * x)) - 1.0f;
}

// NT input loads: stream children_* through (no L3 allocation) so the HBM
// side sees a clean contiguous stream instead of a ~50%-density shredded one.
static __device__ __forceinline__ f32x4 ldnt4(const float* p) {
    return __builtin_nontemporal_load((const f32x4*)p);
}
static __device__ __forceinline__ float ldnt1(const float* p) {
    return __builtin_nontemporal_load(p);
}

// ---- prep: pack Wf (rows 0..255) + Wiou (rows 256..1023) f32 -> bf16 row-major
__global__ void prep(const float* __restrict__ Wf, const float* __restrict__ Wiou,
                     short* __restrict__ ws) {
    const int row = blockIdx.x;          // 0..1023
    const int t   = threadIdx.x;         // 0..63
    const float* src = (row < 256) ? (Wf + (size_t)row * DD)
                                   : (Wiou + (size_t)(row - 256) * DD);
    f32x4 v = *(const f32x4*)(src + t * 4);
    bf16x4 o; o[0] = bfc(v[0]); o[1] = bfc(v[1]); o[2] = bfc(v[2]); o[3] = bfc(v[3]);
    *(bf16x4*)(ws + (size_t)row * DD + t * 4) = o;
}

// ---- main: R4 structure (163us base: 512 thr, BT=16, bf16 LDS dbuf,
// one raw s_barrier per child, lgkm-only drain, h 2-ahead, cm 1-ahead)
// + NON-TEMPORAL loads on children_hidden/children_memory and NT stores.
__global__ __launch_bounds__(NT, 3) void treelstm(
    const float* __restrict__ cmem,   // [C][B][D]
    const float* __restrict__ chid,   // [C][B][D]
    const short* __restrict__ wpk,    // packed bf16: Wf rows 0..255, Wiou 256..1023
    const float* __restrict__ bfv,    // [D]
    const float* __restrict__ biou,   // [3D]
    float* __restrict__ out)          // [2][B][D]
{
    __shared__ __align__(64) unsigned char hb[2][BT * DD * 2];   // 2 x 8 KiB

    const int tid  = threadIdx.x;
    const int lane = tid & 63;
    const int wid  = tid >> 6;     // 0..7
    const int l15  = lane & 15;
    const int l4   = lane >> 4;    // 0..3
    const int b0   = blockIdx.x * BT;
    const int wc0  = wid * 32;     // wave's 32 output columns

    // staging: thread owns (row tid>>5, cols (tid&31)*8 .. +7)
    const int srow = tid >> 5;
    const int scol = (tid & 31) * 8;
    const float* hg = chid + (size_t)(b0 + srow) * DD + scol;
    const int wb = srow * 512 + ((scol * 2) ^ ((srow & 7) << 4));

    // issue h(0) first (Wf-frag setup hides its latency)
    f32x4 q0 = ldnt4(hg);
    f32x4 q1 = ldnt4(hg + 4);

    // Wf B-frags from packed bf16: 2 n-frags x 8 k = 32 VGPR, no packs
    bf16x8 wfr[2][8];
    float bfr[2];
#pragma unroll
    for (int n = 0; n < 2; ++n) {
        const short* wr = wpk + (size_t)(wc0 + n * 16 + l15) * DD + l4 * 8;
#pragma unroll
        for (int k = 0; k < 8; ++k) wfr[n][k] = *(const bf16x8*)(wr + k * 32);
        bfr[n] = bfv[wc0 + n * 16 + l15];
    }

    float hs[8], nmv[8];
#pragma unroll
    for (int i = 0; i < 8; ++i) { hs[i] = 0.f; nmv[i] = 0.f; }

    const float* cmp = cmem + (size_t)(b0 + l4 * 4) * DD + wc0 + l15;
    float cmA[8], cmB[8];
    f32x4 p0, p1;

    // ---- prologue: issue h(1), cm(0); then consume h(0): hs+, pack, write buf0
    {
        const float* h1 = hg + SLAB;
        p0 = ldnt4(h1);
        p1 = ldnt4(h1 + 4);
#pragma unroll
        for (int n = 0; n < 2; ++n)
#pragma unroll
            for (int j = 0; j < 4; ++j) cmA[n * 4 + j] = ldnt1(cmp + j * DD + n * 16);
#pragma unroll
        for (int i = 0; i < 4; ++i) { hs[i] += q0[i]; hs[4 + i] += q1[i]; }
        *(bf16x8*)(&hb[0][0] + wb) = pack8(q0, q1);
        // swap so iter 0 sees Q=h(1) in q, P free
        q0 = p0; q1 = p1;
        asm volatile("s_waitcnt lgkmcnt(0)" ::: "memory");
        __builtin_amdgcn_s_barrier();
        __builtin_amdgcn_sched_barrier(0);
    }

// iter c: buf[PAR]=h(c); Q=h(c+1) arriving; CMU=cm(c) arriving.
// loads: P<-h(c+2), CMF<-cm(c+1).  One lgkm drain + barrier per child.
#define CHILD(c, PAR, Q0, Q1, P0, P1, CMU, CMF)                               \
    {                                                                         \
        if ((c) + 2 < CC) {                                                   \
            const float* hn = hg + (size_t)((c) + 2) * SLAB;                  \
            P0 = ldnt4(hn);                                                   \
            P1 = ldnt4(hn + 4);                                               \
        }                                                                     \
        if ((c) + 1 < CC) {                                                   \
            const float* cn = cmp + (size_t)((c) + 1) * SLAB;                 \
            _Pragma("unroll") for (int n = 0; n < 2; ++n)                     \
            _Pragma("unroll") for (int j = 0; j < 4; ++j)                     \
                CMF[n * 4 + j] = ldnt1(cn + j * DD + n * 16);                 \
        }                                                                     \
        f32x4 acc0 = {bfr[0], bfr[0], bfr[0], bfr[0]};                        \
        f32x4 acc1 = {bfr[1], bfr[1], bfr[1], bfr[1]};                        \
        const unsigned char* bc = &hb[PAR][0] + l15 * 512;                    \
        _Pragma("unroll") for (int kk = 0; kk < 8; ++kk) {                    \
            bf16x8 a = *(const bf16x8*)(bc + (((kk << 6) + (l4 << 4)) ^ sw15)); \
            acc0 = __builtin_amdgcn_mfma_f32_16x16x32_bf16(a, wfr[0][kk], acc0, 0, 0, 0); \
            acc1 = __builtin_amdgcn_mfma_f32_16x16x32_bf16(a, wfr[1][kk], acc1, 0, 0, 0); \
        }                                                                     \
        _Pragma("unroll") for (int j = 0; j < 4; ++j) {                       \
            nmv[j]     += sigm(acc0[j]) * CMU[j];                             \
            nmv[4 + j] += sigm(acc1[j]) * CMU[4 + j];                         \
        }                                                                     \
        if ((c) + 1 < CC) {                                                   \
            _Pragma("unroll") for (int i = 0; i < 4; ++i) {                   \
                hs[i] += Q0[i]; hs[4 + i] += Q1[i];                           \
            }                                                                 \
            *(bf16x8*)(&hb[(PAR) ^ 1][0] + wb) = pack8(Q0, Q1);               \
            asm volatile("s_waitcnt lgkmcnt(0)" ::: "memory");                \
            __builtin_amdgcn_s_barrier();                                     \
            __builtin_amdgcn_sched_barrier(0);                                \
        }                                                                     \
    }

    const int sw15 = (l15 & 7) << 4;

    for (int cc = 0; cc < CC; cc += 2) {
        CHILD(cc,     0, q0, q1, p0, p1, cmA, cmB);
        CHILD(cc + 1, 1, p0, p1, q0, q1, cmB, cmA);
    }
#undef CHILD

    // ---- epilogue: hidden_sum -> LDS buf0 (own slot; all waves past barrier 14)
    {
        f32x4 e0 = {hs[0], hs[1], hs[2], hs[3]};
        f32x4 e1 = {hs[4], hs[5], hs[6], hs[7]};
        *(bf16x8*)(&hb[0][0] + wb) = pack8(e0, e1);
    }
    asm volatile("s_waitcnt lgkmcnt(0)" ::: "memory");
    __builtin_amdgcn_s_barrier();
    __builtin_amdgcn_sched_barrier(0);

    bf16x8 afr[8];
    {
        const unsigned char* bc = &hb[0][0] + l15 * 512;
#pragma unroll
        for (int kk = 0; kk < 8; ++kk)
            afr[kk] = *(const bf16x8*)(bc + (((kk << 6) + (l4 << 4)) ^ sw15));
    }

    // iou GEMM from packed Wiou (bf16, rows 256..1023 of wpk): no packs
    float gq[3][8];
#pragma unroll
    for (int q = 0; q < 3; ++q) {
#pragma unroll
        for (int n = 0; n < 2; ++n) {
            const short* wr = wpk + (size_t)(256 + q * 256 + wc0 + n * 16 + l15) * DD + l4 * 8;
            f32x4 acc = {0.f, 0.f, 0.f, 0.f};
#pragma unroll
            for (int kk = 0; kk < 8; ++kk)
                acc = __builtin_amdgcn_mfma_f32_16x16x32_bf16(afr[kk], *(const bf16x8*)(wr + kk * 32), acc, 0, 0, 0);
            float bq = biou[q * 256 + wc0 + n * 16 + l15];
#pragma unroll
            for (int j = 0; j < 4; ++j) gq[q][n * 4 + j] = acc[j] + bq;
        }
    }

    // ---- gates + NT stores (outputs are never re-read on device)
    float* o0 = out + (size_t)(b0 + l4 * 4) * DD + wc0 + l15;
    float* o1 = o0 + SLAB;
#pragma unroll
    for (int n = 0; n < 2; ++n)
#pragma unroll
        for (int j = 0; j < 4; ++j) {
            float ig = sigm(gq[0][n * 4 + j]);
            float og = sigm(gq[1][n * 4 + j]);
            float ug = tanh_(gq[2][n * 4 + j]);
            float mm = nmv[n * 4 + j] + ig * ug;
            float hh = og * tanh_(mm);
            __builtin_nontemporal_store(mm, o0 + j * DD + n * 16);
            __builtin_nontemporal_store(hh, o1 + j * DD + n * 16);
        }
}

extern "C" void kernel_launch(void* const* d_in, const int* in_sizes, int n_in,
                              void* d_out, int out_size, void* d_ws, size_t ws_size,
                              hipStream_t stream) {
    const float* cmem = (const float*)d_in[0];
    const float* chid = (const float*)d_in[1];
    const float* Wf   = (const float*)d_in[2];
    const float* bf   = (const float*)d_in[3];
    const float* Wiou = (const float*)d_in[4];
    const float* biou = (const float*)d_in[5];
    float* out = (float*)d_out;
    short* wpk = (short*)d_ws;    // 1024 x 256 bf16 = 512 KiB

    prep<<<1024, 64, 0, stream>>>(Wf, Wiou, wpk);
    treelstm<<<BB / BT, NT, 0, stream>>>(cmem, chid, wpk, bf, biou, out);
}